// Round 2
// baseline (1727.640 us; speedup 1.0000x reference)
//
#include <hip/hip_runtime.h>
#include <stdint.h>

// Problem constants (B=4, S=2048, K=4096, O=11008, G=128)
#define MDIM 8192   // B*S
#define NDIM 11008  // O
#define KDIM 4096   // K
#define GRP  128

// GEMM geometry: 256x256 tile, BK=64 (2 ks-slabs of 32), 8 waves (2M x 4N),
// 8-phase pipeline (4 phases/K-tile, 2 tiles double-buffered), counted vmcnt.
#define BM 256
#define BN 256
#define BK 64
#define NT   (KDIM / BK)   // 64 k-tiles
#define MT   (MDIM / BM)   // 32
#define NTLS (NDIM / BN)   // 43
#define NWG  (MT * NTLS)   // 1376 (divisible by 8 XCDs)
#define CPX  (NWG / 8)     // 172

typedef __attribute__((ext_vector_type(8))) __bf16 bf16x8;
typedef __attribute__((ext_vector_type(4))) float f32x4;
typedef __attribute__((ext_vector_type(4))) unsigned short u16x4;

static __device__ __forceinline__ unsigned short f2bf(float f) {
    // round-to-nearest-even fp32 -> bf16 (no NaN inputs in this problem)
    union { float f; unsigned int u; } c; c.f = f;
    unsigned int u = c.u;
    u += 0x7fffu + ((u >> 16) & 1u);
    return (unsigned short)(u >> 16);
}

// ---------------------------------------------------------------------------
// Kernel 1: dynamic per-row activation quant -> dequantized bf16
// ---------------------------------------------------------------------------
__global__ __launch_bounds__(256) void quant_x_kernel(const float* __restrict__ x,
                                                      unsigned short* __restrict__ xq) {
    __shared__ float red[256];
    const int row = blockIdx.x;
    const int tid = threadIdx.x;
    const float* xr = x + (size_t)row * KDIM;

    f32x4 v[4];
    float amax = 0.f;
#pragma unroll
    for (int i = 0; i < 4; ++i) {
        v[i] = *(const f32x4*)(xr + 4 * (tid + 256 * i));
        amax = fmaxf(amax, fmaxf(fmaxf(fabsf(v[i].x), fabsf(v[i].y)),
                                 fmaxf(fabsf(v[i].z), fabsf(v[i].w))));
    }
    red[tid] = amax;
    __syncthreads();
    for (int s = 128; s > 0; s >>= 1) {
        if (tid < s) red[tid] = fmaxf(red[tid], red[tid + s]);
        __syncthreads();
    }
    const float scale = fmaxf(red[0], 1e-5f) / 127.0f;

#pragma unroll
    for (int i = 0; i < 4; ++i) {
        u16x4 ov;
        float q;
        q = fminf(fmaxf(rintf(v[i].x / scale), -128.f), 127.f); ov.x = f2bf(q * scale);
        q = fminf(fmaxf(rintf(v[i].y / scale), -128.f), 127.f); ov.y = f2bf(q * scale);
        q = fminf(fmaxf(rintf(v[i].z / scale), -128.f), 127.f); ov.z = f2bf(q * scale);
        q = fminf(fmaxf(rintf(v[i].w / scale), -128.f), 127.f); ov.w = f2bf(q * scale);
        *(u16x4*)(xq + (size_t)row * KDIM + 4 * (tid + 256 * i)) = ov;
    }
}

// ---------------------------------------------------------------------------
// Kernel 2: int4-group weight dequant -> bf16 (O x K row-major = B^T layout)
// ---------------------------------------------------------------------------
__global__ __launch_bounds__(256) void dequant_w_kernel(const int* __restrict__ w,
                                                        const float* __restrict__ sz,
                                                        unsigned short* __restrict__ wq) {
    const int idx = blockIdx.x * 256 + threadIdx.x;
    const int kc = idx & (KDIM / 4 - 1);
    const int o  = idx >> 10;
    const int k0 = kc << 2;
    const int g  = k0 >> 7;
    const float2 szv = *(const float2*)(sz + ((size_t)g * NDIM + o) * 2);
    const float s = szv.x, z = szv.y;
    const int4 wv = *(const int4*)(w + (size_t)o * KDIM + k0);
    u16x4 ov;
    ov.x = f2bf(((float)wv.x - z) * s);
    ov.y = f2bf(((float)wv.y - z) * s);
    ov.z = f2bf(((float)wv.z - z) * s);
    ov.w = f2bf(((float)wv.w - z) * s);
    *(u16x4*)(wq + (size_t)o * KDIM + k0) = ov;
}

// ---------------------------------------------------------------------------
// Kernel 3: bf16 GEMM, C[M,N] = A[M,K] * B[N,K]^T — 256^2 8-phase template.
//  - LDS [buf][ks][256][32] bf16, 128 KiB total, double-buffered per K-tile.
//  - global_load_lds w=16, linear LDS dest + pre-swizzled global k-chunk
//    (chunk c of row r stored at pos c ^ ((r>>1)&3) within its 32-k slab;
//    reader applies the same XOR -> conflict-free ds_read_b128, measured 0
//    SQ_LDS_BANK_CONFLICT at 128²; read pattern identical here).
//  - Staging discipline (every write lands in a region whose last reader
//    finished >=1 barrier earlier; every region staged 6 phases before use):
//      ph1: A-ks1 of t+1 -> other buf      ph2: B-ks1 of t+1 -> other buf, W1
//      ph3: A-ks0 of t+2 -> cur buf        ph4: B-ks0 of t+2 -> cur buf,   W2
//    W1/W2 = s_waitcnt vmcnt(8) BEFORE the phase-end barrier (counted, never 0
//    in steady state; 8 = 4 staging pairs in flight).
//    vmcnt ledger: at W1 outstanding = {A0[t+1],B0[t+1] (prev iter ph3/4),
//    A1[t+1],B1[t+1]} = 8 -> retires A1/B1 of tile t (read at ph3). At W2
//    outstanding = this iter's 4 events = 8 -> retires A0/B0 of tile t+1
//    (read at next ph1).
// ---------------------------------------------------------------------------
#define GLD(g, l)                                                                   \
    __builtin_amdgcn_global_load_lds((const __attribute__((address_space(1))) void*)(g), \
                                     (__attribute__((address_space(3))) void*)(l), 16, 0, 0)

#define LDS_A(ks, row) (*(const bf16x8*)(Ab + (ks) * 8192 + (row) * 32 + sw))
#define LDS_B(ks, row) (*(const bf16x8*)(Bb + (ks) * 8192 + (row) * 32 + sw))

#define MFMA16(MH)                                                                  \
    _Pragma("unroll") for (int i = 0; i < 4; ++i)                                   \
        _Pragma("unroll") for (int j = 0; j < 4; ++j)                               \
            acc[(MH) * 4 + i][j] =                                                  \
                __builtin_amdgcn_mfma_f32_16x16x32_bf16(af[i], bv[j], acc[(MH) * 4 + i][j], 0, 0, 0);

// LDS (128 KiB) caps residency at 1 block/CU regardless of VGPRs, so do NOT
// request min-waves=2 (would cap VGPR at 256 and risk scratch spills for zero
// occupancy gain).
__global__ __launch_bounds__(512, 1) void gemm_bt_kernel(const unsigned short* __restrict__ A,
                                                         const unsigned short* __restrict__ B,
                                                         float* __restrict__ C) {
    __shared__ unsigned short As_f[32768];  // 64 KiB: [2 buf][2 ks][256][32]
    __shared__ unsigned short Bs_f[32768];  // 64 KiB

    const int tid  = threadIdx.x;
    const int lane = tid & 63;
    const int wave = tid >> 6;          // 0..7
    const int quad = lane >> 4;
    const int l16  = lane & 15;
    const int wm   = (wave >> 2) * 128; // 0 / 128
    const int wn   = (wave & 3) * 64;   // 0 / 64 / 128 / 192

    // XCD-aware swizzle (1376 % 8 == 0 -> simple form is bijective), m-fastest
    // within each XCD chunk so the B-panel stays hot in the XCD's L2.
    const int bid  = blockIdx.x;
    const int swzb = (bid & 7) * CPX + (bid >> 3);
    const int bm   = (swzb & (MT - 1)) * BM;
    const int bn   = (swzb / MT) * BN;

    // Staging: thread owns 16 B; row = tid>>2 within a 128-row region,
    // global k-chunk pre-swizzled so linear LDS holds pos c ^ ((row>>1)&3).
    const int trow = tid >> 2;                               // 0..127
    const int kswz = (((tid & 3) ^ ((tid >> 3) & 3)) << 3);  // elements
    const unsigned short* pA0 = A + (size_t)(bm + trow) * KDIM + kswz;
    const unsigned short* pA1 = pA0 + (size_t)128 * KDIM;
    const unsigned short* pB0 = B + (size_t)(bn + trow) * KDIM + kswz;
    const unsigned short* pB1 = pB0 + (size_t)128 * KDIM;
    unsigned short* dA = As_f + tid * 8;  // + buf*16384 + ks*8192 + rh*4096
    unsigned short* dB = Bs_f + tid * 8;

    // Reader-side XOR: frag row = 16-aligned base + l16 -> (row>>1)&3 == (l16>>1)&3.
    const int sw = ((quad ^ ((l16 >> 1) & 3)) << 3);

    f32x4 acc[8][4];
#pragma unroll
    for (int i = 0; i < 8; ++i)
#pragma unroll
        for (int j = 0; j < 4; ++j) acc[i][j] = (f32x4){0.f, 0.f, 0.f, 0.f};

    // Prologue: t0 ks0 | t0 ks1 | t1 ks0  (12 loads); wait oldest 4 (t0 ks0).
    GLD(pA0,      dA);          GLD(pA1,      dA + 4096);
    GLD(pB0,      dB);          GLD(pB1,      dB + 4096);
    GLD(pA0 + 32, dA + 8192);   GLD(pA1 + 32, dA + 12288);
    GLD(pB0 + 32, dB + 8192);   GLD(pB1 + 32, dB + 12288);
    GLD(pA0 + 64, dA + 16384);  GLD(pA1 + 64, dA + 20480);
    GLD(pB0 + 64, dB + 16384);  GLD(pB1 + 64, dB + 20480);
    asm volatile("s_waitcnt vmcnt(8)" ::: "memory");
    __builtin_amdgcn_s_barrier();

    int buf = 0;
    for (int t = 0; t < NT; ++t) {
        const unsigned short* Ab = As_f + buf * 16384;
        const unsigned short* Bb = Bs_f + buf * 16384;
        unsigned short* dAn = dA + (buf ^ 1) * 16384;  // tile t+1 buffer (free)
        unsigned short* dBn = dB + (buf ^ 1) * 16384;
        unsigned short* dAc = dA + buf * 16384;        // tile t+2 -> consumed regions
        unsigned short* dBc = dB + buf * 16384;

        bf16x8 af[4], bv[4];

        // ---- phase 1: (mh=0, ks=0) ----
#pragma unroll
        for (int i = 0; i < 4; ++i) af[i] = LDS_A(0, wm + i * 16 + l16);
#pragma unroll
        for (int j = 0; j < 4; ++j) bv[j] = LDS_B(0, wn + j * 16 + l16);
        if (t < NT - 1) {
            GLD(pA0 + (t + 1) * 64 + 32, dAn + 8192);
            GLD(pA1 + (t + 1) * 64 + 32, dAn + 12288);
        }
        __builtin_amdgcn_s_barrier();
        asm volatile("s_waitcnt lgkmcnt(0)" ::: "memory");
        __builtin_amdgcn_sched_barrier(0);
        __builtin_amdgcn_s_setprio(1);
        MFMA16(0);
        __builtin_amdgcn_s_setprio(0);
        __builtin_amdgcn_s_barrier();

        // ---- phase 2: (mh=1, ks=0), reuse bv ----
#pragma unroll
        for (int i = 0; i < 4; ++i) af[i] = LDS_A(0, wm + 64 + i * 16 + l16);
        if (t < NT - 1) {
            GLD(pB0 + (t + 1) * 64 + 32, dBn + 8192);
            GLD(pB1 + (t + 1) * 64 + 32, dBn + 12288);
        }
        __builtin_amdgcn_s_barrier();
        asm volatile("s_waitcnt lgkmcnt(0)" ::: "memory");
        __builtin_amdgcn_sched_barrier(0);
        __builtin_amdgcn_s_setprio(1);
        MFMA16(1);
        __builtin_amdgcn_s_setprio(0);
        if (t < NT - 1) asm volatile("s_waitcnt vmcnt(8)" ::: "memory");  // W1
        else            asm volatile("s_waitcnt vmcnt(0)" ::: "memory");
        __builtin_amdgcn_s_barrier();

        // ---- phase 3: (mh=0, ks=1) ----
#pragma unroll
        for (int i = 0; i < 4; ++i) af[i] = LDS_A(1, wm + i * 16 + l16);
#pragma unroll
        for (int j = 0; j < 4; ++j) bv[j] = LDS_B(1, wn + j * 16 + l16);
        if (t < NT - 2) {
            GLD(pA0 + (t + 2) * 64, dAc);
            GLD(pA1 + (t + 2) * 64, dAc + 4096);
        }
        __builtin_amdgcn_s_barrier();
        asm volatile("s_waitcnt lgkmcnt(0)" ::: "memory");
        __builtin_amdgcn_sched_barrier(0);
        __builtin_amdgcn_s_setprio(1);
        MFMA16(0);
        __builtin_amdgcn_s_setprio(0);
        __builtin_amdgcn_s_barrier();

        // ---- phase 4: (mh=1, ks=1), reuse bv ----
#pragma unroll
        for (int i = 0; i < 4; ++i) af[i] = LDS_A(1, wm + 64 + i * 16 + l16);
        if (t < NT - 2) {
            GLD(pB0 + (t + 2) * 64, dBc);
            GLD(pB1 + (t + 2) * 64, dBc + 4096);
        }
        __builtin_amdgcn_s_barrier();
        asm volatile("s_waitcnt lgkmcnt(0)" ::: "memory");
        __builtin_amdgcn_sched_barrier(0);
        __builtin_amdgcn_s_setprio(1);
        MFMA16(1);
        __builtin_amdgcn_s_setprio(0);
        if (t < NT - 2) asm volatile("s_waitcnt vmcnt(8)" ::: "memory");  // W2
        else            asm volatile("s_waitcnt vmcnt(0)" ::: "memory");
        __builtin_amdgcn_s_barrier();

        buf ^= 1;
    }

    // Epilogue: C/D layout col=l16 (n), row=quad*4+reg (m)
#pragma unroll
    for (int mi = 0; mi < 8; ++mi) {
        const int gm = bm + wm + mi * 16 + quad * 4;
#pragma unroll
        for (int r = 0; r < 4; ++r) {
            float* crow = C + (size_t)(gm + r) * NDIM + bn + wn + l16;
#pragma unroll
            for (int j = 0; j < 4; ++j) crow[j * 16] = acc[mi][j][r];
        }
    }
}

// ---------------------------------------------------------------------------
extern "C" void kernel_launch(void* const* d_in, const int* in_sizes, int n_in,
                              void* d_out, int out_size, void* d_ws, size_t ws_size,
                              hipStream_t stream) {
    const float* x  = (const float*)d_in[0];           // (4,2048,4096) fp32
    const int*   w  = (const int*)d_in[1];             // (11008,4096) int
    const float* sz = (const float*)d_in[2];           // (32,11008,2) fp32
    float* out = (float*)d_out;                        // (4,2048,11008) fp32

    unsigned short* xq = (unsigned short*)d_ws;
    unsigned short* wq = (unsigned short*)((char*)d_ws + (size_t)MDIM * KDIM * 2);

    quant_x_kernel<<<MDIM, 256, 0, stream>>>(x, xq);
    dequant_w_kernel<<<(NDIM * KDIM / 4) / 256, 256, 0, stream>>>(w, sz, wq);
    gemm_bt_kernel<<<NWG, 512, 0, stream>>>(xq, wq, out);
}

// Round 3
// 1722.391 us; speedup vs baseline: 1.0030x; 1.0030x over previous
//
#include <hip/hip_runtime.h>
#include <stdint.h>

// Problem constants (B=4, S=2048, K=4096, O=11008, G=128)
#define MDIM 8192   // B*S
#define NDIM 11008  // O
#define KDIM 4096   // K
#define GRP  128

// GEMM geometry: 256x256 tile, BK=64 (2 ks-slabs of 32), 8 waves (2M x 4N),
// 4 phases/K-tile, 2 K-tiles double-buffered in LDS, counted vmcnt.
#define BM 256
#define BN 256
#define BK 64
#define NT   (KDIM / BK)   // 64 k-tiles
#define MT   (MDIM / BM)   // 32
#define NTLS (NDIM / BN)   // 43
#define NWG  (MT * NTLS)   // 1376 (divisible by 8 XCDs)
#define CPX  (NWG / 8)     // 172

typedef __attribute__((ext_vector_type(8))) __bf16 bf16x8;
typedef __attribute__((ext_vector_type(4))) float f32x4;
typedef __attribute__((ext_vector_type(4))) unsigned short u16x4;

static __device__ __forceinline__ unsigned short f2bf(float f) {
    // round-to-nearest-even fp32 -> bf16 (no NaN inputs in this problem)
    union { float f; unsigned int u; } c; c.f = f;
    unsigned int u = c.u;
    u += 0x7fffu + ((u >> 16) & 1u);
    return (unsigned short)(u >> 16);
}

// ---------------------------------------------------------------------------
// Kernel 1: dynamic per-row activation quant -> dequantized bf16
// ---------------------------------------------------------------------------
__global__ __launch_bounds__(256) void quant_x_kernel(const float* __restrict__ x,
                                                      unsigned short* __restrict__ xq) {
    __shared__ float red[256];
    const int row = blockIdx.x;
    const int tid = threadIdx.x;
    const float* xr = x + (size_t)row * KDIM;

    f32x4 v[4];
    float amax = 0.f;
#pragma unroll
    for (int i = 0; i < 4; ++i) {
        v[i] = *(const f32x4*)(xr + 4 * (tid + 256 * i));
        amax = fmaxf(amax, fmaxf(fmaxf(fabsf(v[i].x), fabsf(v[i].y)),
                                 fmaxf(fabsf(v[i].z), fabsf(v[i].w))));
    }
    red[tid] = amax;
    __syncthreads();
    for (int s = 128; s > 0; s >>= 1) {
        if (tid < s) red[tid] = fmaxf(red[tid], red[tid + s]);
        __syncthreads();
    }
    const float scale = fmaxf(red[0], 1e-5f) / 127.0f;

#pragma unroll
    for (int i = 0; i < 4; ++i) {
        u16x4 ov;
        float q;
        q = fminf(fmaxf(rintf(v[i].x / scale), -128.f), 127.f); ov.x = f2bf(q * scale);
        q = fminf(fmaxf(rintf(v[i].y / scale), -128.f), 127.f); ov.y = f2bf(q * scale);
        q = fminf(fmaxf(rintf(v[i].z / scale), -128.f), 127.f); ov.z = f2bf(q * scale);
        q = fminf(fmaxf(rintf(v[i].w / scale), -128.f), 127.f); ov.w = f2bf(q * scale);
        *(u16x4*)(xq + (size_t)row * KDIM + 4 * (tid + 256 * i)) = ov;
    }
}

// ---------------------------------------------------------------------------
// Kernel 2: int4-group weight dequant -> bf16 (O x K row-major = B^T layout)
// ---------------------------------------------------------------------------
__global__ __launch_bounds__(256) void dequant_w_kernel(const int* __restrict__ w,
                                                        const float* __restrict__ sz,
                                                        unsigned short* __restrict__ wq) {
    const int idx = blockIdx.x * 256 + threadIdx.x;
    const int kc = idx & (KDIM / 4 - 1);
    const int o  = idx >> 10;
    const int k0 = kc << 2;
    const int g  = k0 >> 7;
    const float2 szv = *(const float2*)(sz + ((size_t)g * NDIM + o) * 2);
    const float s = szv.x, z = szv.y;
    const int4 wv = *(const int4*)(w + (size_t)o * KDIM + k0);
    u16x4 ov;
    ov.x = f2bf(((float)wv.x - z) * s);
    ov.y = f2bf(((float)wv.y - z) * s);
    ov.z = f2bf(((float)wv.z - z) * s);
    ov.w = f2bf(((float)wv.w - z) * s);
    *(u16x4*)(wq + (size_t)o * KDIM + k0) = ov;
}

// ---------------------------------------------------------------------------
// Kernel 3: bf16 GEMM, C[M,N] = A[M,K] * B[N,K]^T — 256^2 4-phase/K-tile.
//  - LDS [buf][ks][256][32] bf16, 128 KiB, double-buffered per K-tile.
//  - global_load_lds w=16, linear LDS dest + pre-swizzled global k-chunk;
//    reader applies the same XOR -> conflict-free ds_read_b128 (0 conflicts
//    measured).
//  - READ->MFMA path is UNPINNED: fragment loads are compiler-visible, hipcc
//    emits progressive lgkmcnt(N) per consuming MFMA, so MFMA issue overlaps
//    the LDS read drain (round-2 fix: the previous pre-MFMA lgkmcnt(0) +
//    sched_barrier(0) serialized read-drain and MFMA -> 25% MfmaUtil).
//  - Race-freedom invariant kept via TRAILING lgkmcnt(0) per phase: no wave
//    crosses the phase-end barrier with current-region reads in flight, so a
//    later phase's global_load_lds DMA can never overwrite a pending read.
//  - Staging (region staged ~4-5 phases before use; counted vmcnt, never 0):
//      ph1: A-ks1[t+1] -> other buf       ph2: B-ks1[t+1] -> other buf, W1
//      ph3: A-ks0[t+2] -> cur buf         ph4: B-ks0[t+2] -> cur buf,   W2
//    W1 vmcnt(8) retires A/B-ks1[t] (read ph3/ph4); W2 retires A/B-ks0[t+1]
//    (read next ph1/ph2). 8 = 4 staging pairs in flight.
// ---------------------------------------------------------------------------
#define GLD(g, l)                                                                   \
    __builtin_amdgcn_global_load_lds((const __attribute__((address_space(1))) void*)(g), \
                                     (__attribute__((address_space(3))) void*)(l), 16, 0, 0)

#define LDS_A(ks, row) (*(const bf16x8*)(Ab + (ks) * 8192 + (row) * 32 + sw))
#define LDS_B(ks, row) (*(const bf16x8*)(Bb + (ks) * 8192 + (row) * 32 + sw))

#define MFMA16(MH)                                                                  \
    _Pragma("unroll") for (int i = 0; i < 4; ++i)                                   \
        _Pragma("unroll") for (int j = 0; j < 4; ++j)                               \
            acc[(MH) * 4 + i][j] =                                                  \
                __builtin_amdgcn_mfma_f32_16x16x32_bf16(af[i], bv[j], acc[(MH) * 4 + i][j], 0, 0, 0);

// LDS (128 KiB) caps residency at 1 block/CU; don't request min-waves=2.
__global__ __launch_bounds__(512, 1) void gemm_bt_kernel(const unsigned short* __restrict__ A,
                                                         const unsigned short* __restrict__ B,
                                                         float* __restrict__ C) {
    __shared__ unsigned short As_f[32768];  // 64 KiB: [2 buf][2 ks][256][32]
    __shared__ unsigned short Bs_f[32768];  // 64 KiB

    const int tid  = threadIdx.x;
    const int lane = tid & 63;
    const int wave = tid >> 6;          // 0..7
    const int quad = lane >> 4;
    const int l16  = lane & 15;
    const int wm   = (wave >> 2) * 128; // 0 / 128
    const int wn   = (wave & 3) * 64;   // 0 / 64 / 128 / 192

    // XCD-aware swizzle (1376 % 8 == 0 -> simple form is bijective), m-fastest
    // within each XCD chunk so the B-panel stays hot in the XCD's L2.
    const int bid  = blockIdx.x;
    const int swzb = (bid & 7) * CPX + (bid >> 3);
    const int bm   = (swzb & (MT - 1)) * BM;
    const int bn   = (swzb / MT) * BN;

    // Staging: thread owns 16 B; row = tid>>2 within a 128-row region,
    // global k-chunk pre-swizzled so linear LDS holds pos c ^ ((row>>1)&3).
    const int trow = tid >> 2;                               // 0..127
    const int kswz = (((tid & 3) ^ ((tid >> 3) & 3)) << 3);  // elements
    const unsigned short* pA0 = A + (size_t)(bm + trow) * KDIM + kswz;
    const unsigned short* pA1 = pA0 + (size_t)128 * KDIM;
    const unsigned short* pB0 = B + (size_t)(bn + trow) * KDIM + kswz;
    const unsigned short* pB1 = pB0 + (size_t)128 * KDIM;
    unsigned short* dA = As_f + tid * 8;  // + buf*16384 + ks*8192 + rh*4096
    unsigned short* dB = Bs_f + tid * 8;

    // Reader-side XOR: frag row = 16-aligned base + l16 -> (row>>1)&3 == (l16>>1)&3.
    const int sw = ((quad ^ ((l16 >> 1) & 3)) << 3);

    f32x4 acc[8][4];
#pragma unroll
    for (int i = 0; i < 8; ++i)
#pragma unroll
        for (int j = 0; j < 4; ++j) acc[i][j] = (f32x4){0.f, 0.f, 0.f, 0.f};

    // Prologue: t0 ks0 | t0 ks1 | t1 ks0  (12 loads); wait oldest 4 (t0 ks0).
    GLD(pA0,      dA);          GLD(pA1,      dA + 4096);
    GLD(pB0,      dB);          GLD(pB1,      dB + 4096);
    GLD(pA0 + 32, dA + 8192);   GLD(pA1 + 32, dA + 12288);
    GLD(pB0 + 32, dB + 8192);   GLD(pB1 + 32, dB + 12288);
    GLD(pA0 + 64, dA + 16384);  GLD(pA1 + 64, dA + 20480);
    GLD(pB0 + 64, dB + 16384);  GLD(pB1 + 64, dB + 20480);
    asm volatile("s_waitcnt vmcnt(8)" ::: "memory");
    __builtin_amdgcn_s_barrier();

    int buf = 0;
    for (int t = 0; t < NT; ++t) {
        const unsigned short* Ab = As_f + buf * 16384;
        const unsigned short* Bb = Bs_f + buf * 16384;
        unsigned short* dAn = dA + (buf ^ 1) * 16384;  // tile t+1 buffer (free)
        unsigned short* dBn = dB + (buf ^ 1) * 16384;
        unsigned short* dAc = dA + buf * 16384;        // tile t+2 -> consumed regions
        unsigned short* dBc = dB + buf * 16384;

        bf16x8 af[4], bv[4];

        // ---- phase 1: (mh=0, ks=0) ----
#pragma unroll
        for (int i = 0; i < 4; ++i) af[i] = LDS_A(0, wm + i * 16 + l16);
#pragma unroll
        for (int j = 0; j < 4; ++j) bv[j] = LDS_B(0, wn + j * 16 + l16);
        if (t < NT - 1) {
            GLD(pA0 + (t + 1) * 64 + 32, dAn + 8192);
            GLD(pA1 + (t + 1) * 64 + 32, dAn + 12288);
        }
        __builtin_amdgcn_s_barrier();
        __builtin_amdgcn_s_setprio(1);
        MFMA16(0);
        __builtin_amdgcn_s_setprio(0);
        asm volatile("s_waitcnt lgkmcnt(0)" ::: "memory");  // all my reads done
        __builtin_amdgcn_s_barrier();

        // ---- phase 2: (mh=1, ks=0), reuse bv ----
#pragma unroll
        for (int i = 0; i < 4; ++i) af[i] = LDS_A(0, wm + 64 + i * 16 + l16);
        if (t < NT - 1) {
            GLD(pB0 + (t + 1) * 64 + 32, dBn + 8192);
            GLD(pB1 + (t + 1) * 64 + 32, dBn + 12288);
        }
        __builtin_amdgcn_s_barrier();
        __builtin_amdgcn_s_setprio(1);
        MFMA16(1);
        __builtin_amdgcn_s_setprio(0);
        if (t < NT - 1) asm volatile("s_waitcnt vmcnt(8)" ::: "memory");  // W1
        else            asm volatile("s_waitcnt vmcnt(0)" ::: "memory");
        asm volatile("s_waitcnt lgkmcnt(0)" ::: "memory");
        __builtin_amdgcn_s_barrier();

        // ---- phase 3: (mh=0, ks=1) ----
#pragma unroll
        for (int i = 0; i < 4; ++i) af[i] = LDS_A(1, wm + i * 16 + l16);
#pragma unroll
        for (int j = 0; j < 4; ++j) bv[j] = LDS_B(1, wn + j * 16 + l16);
        if (t < NT - 2) {
            GLD(pA0 + (t + 2) * 64, dAc);
            GLD(pA1 + (t + 2) * 64, dAc + 4096);
        }
        __builtin_amdgcn_s_barrier();
        __builtin_amdgcn_s_setprio(1);
        MFMA16(0);
        __builtin_amdgcn_s_setprio(0);
        asm volatile("s_waitcnt lgkmcnt(0)" ::: "memory");
        __builtin_amdgcn_s_barrier();

        // ---- phase 4: (mh=1, ks=1), reuse bv ----
#pragma unroll
        for (int i = 0; i < 4; ++i) af[i] = LDS_A(1, wm + 64 + i * 16 + l16);
        if (t < NT - 2) {
            GLD(pB0 + (t + 2) * 64, dBc);
            GLD(pB1 + (t + 2) * 64, dBc + 4096);
        }
        __builtin_amdgcn_s_barrier();
        __builtin_amdgcn_s_setprio(1);
        MFMA16(1);
        __builtin_amdgcn_s_setprio(0);
        if (t < NT - 2) asm volatile("s_waitcnt vmcnt(8)" ::: "memory");  // W2
        else            asm volatile("s_waitcnt vmcnt(0)" ::: "memory");
        asm volatile("s_waitcnt lgkmcnt(0)" ::: "memory");
        __builtin_amdgcn_s_barrier();

        buf ^= 1;
    }

    // Epilogue: C/D layout col=l16 (n), row=quad*4+reg (m)
#pragma unroll
    for (int mi = 0; mi < 8; ++mi) {
        const int gm = bm + wm + mi * 16 + quad * 4;
#pragma unroll
        for (int r = 0; r < 4; ++r) {
            float* crow = C + (size_t)(gm + r) * NDIM + bn + wn + l16;
#pragma unroll
            for (int j = 0; j < 4; ++j) crow[j * 16] = acc[mi][j][r];
        }
    }
}

// ---------------------------------------------------------------------------
extern "C" void kernel_launch(void* const* d_in, const int* in_sizes, int n_in,
                              void* d_out, int out_size, void* d_ws, size_t ws_size,
                              hipStream_t stream) {
    const float* x  = (const float*)d_in[0];           // (4,2048,4096) fp32
    const int*   w  = (const int*)d_in[1];             // (11008,4096) int
    const float* sz = (const float*)d_in[2];           // (32,11008,2) fp32
    float* out = (float*)d_out;                        // (4,2048,11008) fp32

    unsigned short* xq = (unsigned short*)d_ws;
    unsigned short* wq = (unsigned short*)((char*)d_ws + (size_t)MDIM * KDIM * 2);

    quant_x_kernel<<<MDIM, 256, 0, stream>>>(x, xq);
    dequant_w_kernel<<<(NDIM * KDIM / 4) / 256, 256, 0, stream>>>(w, sz, wq);
    gemm_bt_kernel<<<NWG, 512, 0, stream>>>(xq, wq, out);
}

// Round 4
// 1315.462 us; speedup vs baseline: 1.3133x; 1.3093x over previous
//
#include <hip/hip_runtime.h>
#include <stdint.h>

// Problem constants (B=4, S=2048, K=4096, O=11008, G=128)
#define MDIM 8192   // B*S
#define NDIM 11008  // O
#define KDIM 4096   // K
#define GRP  128

// GEMM geometry: 256x256 tile, BK=64 (2 ks-slabs of 32), 8 waves (2M x 4N),
// 4 phases/K-tile, 2 K-tiles double-buffered in LDS, counted vmcnt.
#define BM 256
#define BN 256
#define BK 64
#define NT   (KDIM / BK)   // 64 k-tiles
#define MT   (MDIM / BM)   // 32
#define NTLS (NDIM / BN)   // 43
#define NWG  (MT * NTLS)   // 1376 (divisible by 8 XCDs)
#define CPX  (NWG / 8)     // 172

typedef __attribute__((ext_vector_type(8))) __bf16 bf16x8;
typedef __attribute__((ext_vector_type(4))) float f32x4;
typedef __attribute__((ext_vector_type(4))) unsigned short u16x4;

static __device__ __forceinline__ unsigned short f2bf(float f) {
    // round-to-nearest-even fp32 -> bf16 (no NaN inputs in this problem)
    union { float f; unsigned int u; } c; c.f = f;
    unsigned int u = c.u;
    u += 0x7fffu + ((u >> 16) & 1u);
    return (unsigned short)(u >> 16);
}

// ---------------------------------------------------------------------------
// Kernel 1: dynamic per-row activation quant -> dequantized bf16
// ---------------------------------------------------------------------------
__global__ __launch_bounds__(256) void quant_x_kernel(const float* __restrict__ x,
                                                      unsigned short* __restrict__ xq) {
    __shared__ float red[256];
    const int row = blockIdx.x;
    const int tid = threadIdx.x;
    const float* xr = x + (size_t)row * KDIM;

    f32x4 v[4];
    float amax = 0.f;
#pragma unroll
    for (int i = 0; i < 4; ++i) {
        v[i] = *(const f32x4*)(xr + 4 * (tid + 256 * i));
        amax = fmaxf(amax, fmaxf(fmaxf(fabsf(v[i].x), fabsf(v[i].y)),
                                 fmaxf(fabsf(v[i].z), fabsf(v[i].w))));
    }
    red[tid] = amax;
    __syncthreads();
    for (int s = 128; s > 0; s >>= 1) {
        if (tid < s) red[tid] = fmaxf(red[tid], red[tid + s]);
        __syncthreads();
    }
    const float scale = fmaxf(red[0], 1e-5f) / 127.0f;

#pragma unroll
    for (int i = 0; i < 4; ++i) {
        u16x4 ov;
        float q;
        q = fminf(fmaxf(rintf(v[i].x / scale), -128.f), 127.f); ov.x = f2bf(q * scale);
        q = fminf(fmaxf(rintf(v[i].y / scale), -128.f), 127.f); ov.y = f2bf(q * scale);
        q = fminf(fmaxf(rintf(v[i].z / scale), -128.f), 127.f); ov.z = f2bf(q * scale);
        q = fminf(fmaxf(rintf(v[i].w / scale), -128.f), 127.f); ov.w = f2bf(q * scale);
        *(u16x4*)(xq + (size_t)row * KDIM + 4 * (tid + 256 * i)) = ov;
    }
}

// ---------------------------------------------------------------------------
// Kernel 2: int4-group weight dequant -> bf16 (O x K row-major = B^T layout)
// ---------------------------------------------------------------------------
__global__ __launch_bounds__(256) void dequant_w_kernel(const int* __restrict__ w,
                                                        const float* __restrict__ sz,
                                                        unsigned short* __restrict__ wq) {
    const int idx = blockIdx.x * 256 + threadIdx.x;
    const int kc = idx & (KDIM / 4 - 1);
    const int o  = idx >> 10;
    const int k0 = kc << 2;
    const int g  = k0 >> 7;
    const float2 szv = *(const float2*)(sz + ((size_t)g * NDIM + o) * 2);
    const float s = szv.x, z = szv.y;
    const int4 wv = *(const int4*)(w + (size_t)o * KDIM + k0);
    u16x4 ov;
    ov.x = f2bf(((float)wv.x - z) * s);
    ov.y = f2bf(((float)wv.y - z) * s);
    ov.z = f2bf(((float)wv.z - z) * s);
    ov.w = f2bf(((float)wv.w - z) * s);
    *(u16x4*)(wq + (size_t)o * KDIM + k0) = ov;
}

// ---------------------------------------------------------------------------
// Kernel 3: bf16 GEMM, C[M,N] = A[M,K] * B[N,K]^T — 256^2 4-phase/K-tile.
//  - LDS [buf][ks][256][32] bf16, 128 KiB, double-buffered per K-tile.
//  - global_load_lds w=16, linear LDS dest + pre-swizzled global k-chunk;
//    reader applies same XOR -> conflict-free ds_read_b128 (0 conflicts meas.)
//  - Fragment reads are INLINE-ASM ds_read_b128 (round-3 fix): compiler-visible
//    LDS reads may-alias the outstanding global_load_lds LDS-DMA writes, so the
//    memory legalizer inserts hidden vmcnt drains before every phase's reads —
//    draining the HBM prefetch queue each phase (the measured ~1600cy/phase
//    stall, MfmaUtil 24%). Asm reads are invisible to the legalizer; ordering
//    is owned by the explicit W1/W2 counted vmcnt + barriers. Per rule #18:
//    manual s_waitcnt lgkmcnt(0) + sched_barrier(0) before each MFMA cluster.
//  - Staging ledger (events E1..E4 per tile, 2 loads each; never drain to 0):
//      ph1: E1=A-ks1[t+1]->buf^1   ph2: E2=B-ks1[t+1]->buf^1, W1
//      ph3: E3=A-ks0[t+2]->buf     ph4: E4=B-ks0[t+2]->buf,   W2
//    W1(t)=vmcnt(8): retires E1/E2(t-1) = A/B-ks1[t], read ph3/ph4(t).
//    W2(t)=vmcnt(8): retires E3/E4(t-1) = A/B-ks0[t+1], read ph1/ph2(t+1).
//    TAIL: at t=NT-2, E3/E4 are not issued, so W2 must be vmcnt(4) to retire
//    E3/E4(NT-3) = ks0[NT-1] (vmcnt(8) would leave them in flight -> race).
// ---------------------------------------------------------------------------
#define GLD(g, l)                                                                   \
    __builtin_amdgcn_global_load_lds((const __attribute__((address_space(1))) void*)(g), \
                                     (__attribute__((address_space(3))) void*)(l), 16, 0, 0)

// Inline-asm LDS read: addr VGPR + compile-time byte offset (imm must be literal).
#define DSR(dst, addr, imm) \
    asm volatile("ds_read_b128 %0, %1 offset:" #imm : "=v"(dst) : "v"(addr))

#define MFMA16(MH)                                                                  \
    _Pragma("unroll") for (int i = 0; i < 4; ++i)                                   \
        _Pragma("unroll") for (int j = 0; j < 4; ++j)                               \
            acc[(MH) * 4 + i][j] =                                                  \
                __builtin_amdgcn_mfma_f32_16x16x32_bf16(af[i], bv[j], acc[(MH) * 4 + i][j], 0, 0, 0);

#define WAIT_LGKM_SB()                                          \
    asm volatile("s_waitcnt lgkmcnt(0)" ::: "memory");          \
    __builtin_amdgcn_sched_barrier(0)

// LDS (128 KiB) caps residency at 1 block/CU; don't request min-waves=2.
__global__ __launch_bounds__(512, 1) void gemm_bt_kernel(const unsigned short* __restrict__ A,
                                                         const unsigned short* __restrict__ B,
                                                         float* __restrict__ C) {
    __shared__ unsigned short As_f[32768];  // 64 KiB: [2 buf][2 ks][256][32]
    __shared__ unsigned short Bs_f[32768];  // 64 KiB

    const int tid  = threadIdx.x;
    const int lane = tid & 63;
    const int wave = tid >> 6;          // 0..7
    const int quad = lane >> 4;
    const int l16  = lane & 15;
    const int wm   = (wave >> 2) * 128; // 0 / 128
    const int wn   = (wave & 3) * 64;   // 0 / 64 / 128 / 192

    // XCD-aware swizzle (1376 % 8 == 0 -> bijective), m-fastest per XCD chunk.
    const int bid  = blockIdx.x;
    const int swzb = (bid & 7) * CPX + (bid >> 3);
    const int bm   = (swzb & (MT - 1)) * BM;
    const int bn   = (swzb / MT) * BN;

    // Staging: thread owns 16 B; row = tid>>2 within a 128-row region,
    // global k-chunk pre-swizzled so linear LDS holds pos c ^ ((row>>1)&3).
    const int trow = tid >> 2;                               // 0..127
    const int kswz = (((tid & 3) ^ ((tid >> 3) & 3)) << 3);  // elements
    const unsigned short* pA0 = A + (size_t)(bm + trow) * KDIM + kswz;
    const unsigned short* pA1 = pA0 + (size_t)128 * KDIM;
    const unsigned short* pB0 = B + (size_t)(bn + trow) * KDIM + kswz;
    const unsigned short* pB1 = pB0 + (size_t)128 * KDIM;
    unsigned short* dA = As_f + tid * 8;  // + buf*16384 + ks*8192 + rh*4096
    unsigned short* dB = Bs_f + tid * 8;

    // Reader-side XOR: frag row = 16-aligned base + l16 -> (row>>1)&3 == (l16>>1)&3.
    const int sw = ((quad ^ ((l16 >> 1) & 3)) << 3);

    // LDS byte addresses for asm ds_read (AS3 pointer value = LDS offset).
    const unsigned asb = (unsigned)(unsigned long long)(__attribute__((address_space(3))) void*)As_f;
    const unsigned bsb = (unsigned)(unsigned long long)(__attribute__((address_space(3))) void*)Bs_f;
    const unsigned aOff0 = asb + (unsigned)(((wm + l16) * 32 + sw) * 2);
    const unsigned bOff0 = bsb + (unsigned)(((wn + l16) * 32 + sw) * 2);
    // Within a buffer: +1024B per 16 rows; mh=1 -> +4096B; ks=1 -> +16384B.

    f32x4 acc[8][4];
#pragma unroll
    for (int i = 0; i < 8; ++i)
#pragma unroll
        for (int j = 0; j < 4; ++j) acc[i][j] = (f32x4){0.f, 0.f, 0.f, 0.f};

    // Prologue: t0 ks0 | t0 ks1 | t1 ks0  (12 loads); wait oldest 4 (t0 ks0).
    GLD(pA0,      dA);          GLD(pA1,      dA + 4096);
    GLD(pB0,      dB);          GLD(pB1,      dB + 4096);
    GLD(pA0 + 32, dA + 8192);   GLD(pA1 + 32, dA + 12288);
    GLD(pB0 + 32, dB + 8192);   GLD(pB1 + 32, dB + 12288);
    GLD(pA0 + 64, dA + 16384);  GLD(pA1 + 64, dA + 20480);
    GLD(pB0 + 64, dB + 16384);  GLD(pB1 + 64, dB + 20480);
    asm volatile("s_waitcnt vmcnt(8)" ::: "memory");
    __builtin_amdgcn_s_barrier();

    int buf = 0;
    for (int t = 0; t < NT; ++t) {
        const unsigned aP = aOff0 + (unsigned)(buf * 32768);
        const unsigned bP = bOff0 + (unsigned)(buf * 32768);
        unsigned short* dAn = dA + (buf ^ 1) * 16384;  // tile t+1 buffer (free)
        unsigned short* dBn = dB + (buf ^ 1) * 16384;
        unsigned short* dAc = dA + buf * 16384;        // tile t+2 -> consumed regions
        unsigned short* dBc = dB + buf * 16384;

        bf16x8 af[4], bv[4];

        // ---- phase 1: (mh=0, ks=0) ----
        DSR(af[0], aP, 0);    DSR(af[1], aP, 1024);
        DSR(af[2], aP, 2048); DSR(af[3], aP, 3072);
        DSR(bv[0], bP, 0);    DSR(bv[1], bP, 1024);
        DSR(bv[2], bP, 2048); DSR(bv[3], bP, 3072);
        if (t < NT - 1) {
            GLD(pA0 + (t + 1) * 64 + 32, dAn + 8192);
            GLD(pA1 + (t + 1) * 64 + 32, dAn + 12288);
        }
        __builtin_amdgcn_s_barrier();
        WAIT_LGKM_SB();
        __builtin_amdgcn_s_setprio(1);
        MFMA16(0);
        __builtin_amdgcn_s_setprio(0);
        __builtin_amdgcn_s_barrier();

        // ---- phase 2: (mh=1, ks=0), reuse bv ----
        DSR(af[0], aP, 4096); DSR(af[1], aP, 5120);
        DSR(af[2], aP, 6144); DSR(af[3], aP, 7168);
        if (t < NT - 1) {
            GLD(pB0 + (t + 1) * 64 + 32, dBn + 8192);
            GLD(pB1 + (t + 1) * 64 + 32, dBn + 12288);
        }
        __builtin_amdgcn_s_barrier();
        WAIT_LGKM_SB();
        __builtin_amdgcn_s_setprio(1);
        MFMA16(1);
        __builtin_amdgcn_s_setprio(0);
        if (t < NT - 1) asm volatile("s_waitcnt vmcnt(8)" ::: "memory");  // W1
        else            asm volatile("s_waitcnt vmcnt(0)" ::: "memory");
        __builtin_amdgcn_s_barrier();

        // ---- phase 3: (mh=0, ks=1) ----
        DSR(af[0], aP, 16384); DSR(af[1], aP, 17408);
        DSR(af[2], aP, 18432); DSR(af[3], aP, 19456);
        DSR(bv[0], bP, 16384); DSR(bv[1], bP, 17408);
        DSR(bv[2], bP, 18432); DSR(bv[3], bP, 19456);
        if (t < NT - 2) {
            GLD(pA0 + (t + 2) * 64, dAc);
            GLD(pA1 + (t + 2) * 64, dAc + 4096);
        }
        __builtin_amdgcn_s_barrier();
        WAIT_LGKM_SB();
        __builtin_amdgcn_s_setprio(1);
        MFMA16(0);
        __builtin_amdgcn_s_setprio(0);
        __builtin_amdgcn_s_barrier();

        // ---- phase 4: (mh=1, ks=1), reuse bv ----
        DSR(af[0], aP, 20480); DSR(af[1], aP, 21504);
        DSR(af[2], aP, 22528); DSR(af[3], aP, 23552);
        if (t < NT - 2) {
            GLD(pB0 + (t + 2) * 64, dBc);
            GLD(pB1 + (t + 2) * 64, dBc + 4096);
        }
        __builtin_amdgcn_s_barrier();
        WAIT_LGKM_SB();
        __builtin_amdgcn_s_setprio(1);
        MFMA16(1);
        __builtin_amdgcn_s_setprio(0);
        if (t < NT - 2)      asm volatile("s_waitcnt vmcnt(8)" ::: "memory");  // W2
        else if (t == NT - 2) asm volatile("s_waitcnt vmcnt(4)" ::: "memory"); // tail: retire ks0[NT-1]
        else                 asm volatile("s_waitcnt vmcnt(0)" ::: "memory");
        __builtin_amdgcn_s_barrier();

        buf ^= 1;
    }

    // Epilogue: C/D layout col=l16 (n), row=quad*4+reg (m)
#pragma unroll
    for (int mi = 0; mi < 8; ++mi) {
        const int gm = bm + wm + mi * 16 + quad * 4;
#pragma unroll
        for (int r = 0; r < 4; ++r) {
            float* crow = C + (size_t)(gm + r) * NDIM + bn + wn + l16;
#pragma unroll
            for (int j = 0; j < 4; ++j) crow[j * 16] = acc[mi][j][r];
        }
    }
}

// ---------------------------------------------------------------------------
extern "C" void kernel_launch(void* const* d_in, const int* in_sizes, int n_in,
                              void* d_out, int out_size, void* d_ws, size_t ws_size,
                              hipStream_t stream) {
    const float* x  = (const float*)d_in[0];           // (4,2048,4096) fp32
    const int*   w  = (const int*)d_in[1];             // (11008,4096) int
    const float* sz = (const float*)d_in[2];           // (32,11008,2) fp32
    float* out = (float*)d_out;                        // (4,2048,11008) fp32

    unsigned short* xq = (unsigned short*)d_ws;
    unsigned short* wq = (unsigned short*)((char*)d_ws + (size_t)MDIM * KDIM * 2);

    quant_x_kernel<<<MDIM, 256, 0, stream>>>(x, xq);
    dequant_w_kernel<<<(NDIM * KDIM / 4) / 256, 256, 0, stream>>>(w, sz, wq);
    gemm_bt_kernel<<<NWG, 512, 0, stream>>>(xq, wq, out);
}